// Round 16
// baseline (419.971 us; speedup 1.0000x reference)
//
#include <hip/hip_runtime.h>
#include <hip/hip_bf16.h>
#include <hip/hip_fp16.h>

#define NN 50000
#define EE 800000
#define ETOT 850000
#define NG 500
#define NBLK ((NN + 255) / 256)  // 196
#define EB ((ETOT + 255) / 256)  // 3321

typedef __attribute__((ext_vector_type(8))) short bf16x8;
typedef __attribute__((ext_vector_type(4))) float f32x4;
typedef _Float16 h2f __attribute__((ext_vector_type(2)));

__device__ __forceinline__ h2f as_h2(unsigned u) {
    union { unsigned u; h2f h; } x;
    x.u = u;
    return x.h;
}

__device__ __forceinline__ unsigned short bf16_rne(float v) {
    unsigned u = __float_as_uint(v);
    unsigned r = u + 0x7FFFu + ((u >> 16) & 1u);
    return (unsigned short)(r >> 16);
}

// Per-block int64/int32 detect: node ids < 50000 => int64 has all-odd-words 0.
__device__ __forceinline__ int detect_stride(const int* __restrict__ ei,
                                             int tid, int* sflag) {
    if (tid < 64) {
        unsigned long long b = __ballot(ei[2 * tid + 1] != 0);
        if (tid == 0) *sflag = b ? 1 : 2;
    }
    __syncthreads();
    return *sflag;
}

// W [K][256] fp32 -> transposed, column-permuted bf16 hi/lo planes [256][K];
// permuted col j = dim*4+head. Also permuted a_src/a_dst.
__device__ __forceinline__ void prepw_one(const float* __restrict__ W,
                                          const float* __restrict__ asrc,
                                          const float* __restrict__ adst,
                                          unsigned short* __restrict__ bhi,
                                          unsigned short* __restrict__ blo,
                                          float* __restrict__ ap,
                                          float* __restrict__ adp,
                                          int K, int t) {
    int j = t / K, k = t - j * K;
    int d = j >> 2, h = j & 3;
    float v = W[k * 256 + h * 64 + d];
    unsigned short hb = bf16_rne(v);
    float hf = __uint_as_float((unsigned)hb << 16);
    bhi[t] = hb;
    blo[t] = bf16_rne(v - hf);
    if (k == 0) { ap[j] = asrc[h * 64 + d]; adp[j] = adst[h * 64 + d]; }
}

// Edge prep (int32 src/dst + self-loops + degree histogram) fused with
// both layers' weight prep in the tail blocks.
__global__ __launch_bounds__(256) void k_prep(
        const int* __restrict__ ei, int* __restrict__ src32,
        int* __restrict__ dst32, int* __restrict__ deg,
        const float* __restrict__ W1, const float* __restrict__ a1s,
        const float* __restrict__ a1d, const float* __restrict__ W2,
        const float* __restrict__ a2s, const float* __restrict__ a2d,
        unsigned short* __restrict__ b1h, unsigned short* __restrict__ b1l,
        unsigned short* __restrict__ b2h, unsigned short* __restrict__ b2l,
        float* __restrict__ ap1, float* __restrict__ adp1,
        float* __restrict__ ap2, float* __restrict__ adp2) {
    int blk = blockIdx.x;
    if (blk >= EB) {  // weight-prep tail
        int g = blk - EB;
        if (g < 128)
            prepw_one(W1, a1s, a1d, b1h, b1l, ap1, adp1, 128, g * 256 + threadIdx.x);
        else
            prepw_one(W2, a2s, a2d, b2h, b2l, ap2, adp2, 64, (g - 128) * 256 + threadIdx.x);
        return;
    }
    __shared__ int sflag;
    int tid = threadIdx.x;
    int st = detect_stride(ei, tid, &sflag);
    int e = blk * 256 + tid;
    if (e >= ETOT) return;
    int s, d;
    if (e < EE) {
        s = ei[(size_t)st * e];
        d = ei[(size_t)st * (EE + e)];
    } else {
        s = d = e - EE;  // self-loop
    }
    src32[e] = s;
    dst32[e] = d;
    atomicAdd(&deg[d], 1);
}

__global__ __launch_bounds__(256) void k_blocksum(const int* __restrict__ deg,
                                                  int* __restrict__ bsum) {
    __shared__ int l[256];
    int gid = blockIdx.x * 256 + threadIdx.x;
    int tid = threadIdx.x;
    l[tid] = (gid < NN) ? deg[gid] : 0;
    __syncthreads();
    for (int o = 128; o > 0; o >>= 1) {
        if (tid < o) l[tid] += l[tid + o];
        __syncthreads();
    }
    if (tid == 0) bsum[blockIdx.x] = l[0];
}

// Each block re-scans bsum[196] locally, then scans its 256-chunk of deg.
__global__ __launch_bounds__(256) void k_scan_final(const int* __restrict__ deg,
                                                    const int* __restrict__ bsum,
                                                    int* __restrict__ rowptr,
                                                    int* __restrict__ cursor) {
    __shared__ int lb[256];
    __shared__ int l[256];
    int tid = threadIdx.x;
    int vb = (tid < NBLK) ? bsum[tid] : 0;
    lb[tid] = vb;
    __syncthreads();
    for (int d = 1; d < 256; d <<= 1) {
        int t = (tid >= d) ? lb[tid - d] : 0;
        __syncthreads();
        lb[tid] += t;
        __syncthreads();
    }
    int boffb = lb[blockIdx.x] - bsum[blockIdx.x];
    int gid = blockIdx.x * 256 + tid;
    int v = (gid < NN) ? deg[gid] : 0;
    l[tid] = v;
    __syncthreads();
    for (int d = 1; d < 256; d <<= 1) {
        int t = (tid >= d) ? l[tid - d] : 0;
        __syncthreads();
        l[tid] += t;
        __syncthreads();
    }
    int ex = l[tid] - v + boffb;
    if (gid < NN) { rowptr[gid] = ex; cursor[gid] = ex; }
    if (gid == 0) rowptr[NN] = ETOT;
}

__global__ __launch_bounds__(256) void k_scatter(const int* __restrict__ src32,
                                                 const int* __restrict__ dst32,
                                                 int* __restrict__ cursor,
                                                 int* __restrict__ csr_src) {
    int e = blockIdx.x * 256 + threadIdx.x;
    if (e >= ETOT) return;
    int pos = atomicAdd(&cursor[dst32[e]], 1);
    csr_src[pos] = src32[e];
}

// C^T formulation: D = Btp-tile * A-tile via MFMA (operands swapped vs r12).
// D layout: lane&15 = NODE, regs = 4 CONTIGUOUS permuted n-cols -> one packed
// 8B h16 store per tile per lane (was 8 scalar 2B stores per node), and the
// alpha epilogue accumulates per-head in regs (j&3 == reg) with no atomics.
// Wave = 16 nodes, grid = 3125 (50000/16 exact) -> ~3 waves/SIMD (r12 had
// 1.5: wave-starved, latency fully exposed). n-tiles processed in pairs for
// 2 independent MFMA chains (ILP).
template <int K>
__global__ __launch_bounds__(64) void k_gemm_mfma(
        const float* __restrict__ A,
        const unsigned short* __restrict__ Bhi,
        const unsigned short* __restrict__ Blo,
        const float* __restrict__ aperm,
        const float* __restrict__ adperm,
        __half* __restrict__ C16,
        float* __restrict__ os,
        float* __restrict__ od) {
    const int NC = K / 32;
    int lane = threadIdx.x;
    int l = lane & 15, q = lane >> 4;
    int m0 = blockIdx.x * 16;

    // Y = A^T fragments ("B" operand): lane = node, k = q*8+j
    bf16x8 yhi[NC], ylo[NC];
    {
        const float* arow = A + (size_t)(m0 + l) * K + q * 8;
#pragma unroll
        for (int c = 0; c < NC; ++c) {
            float4 v0 = *(const float4*)(arow + c * 32);
            float4 v1 = *(const float4*)(arow + c * 32 + 4);
            float vv[8] = {v0.x, v0.y, v0.z, v0.w, v1.x, v1.y, v1.z, v1.w};
#pragma unroll
            for (int j = 0; j < 8; ++j) {
                unsigned short hb = bf16_rne(vv[j]);
                float hf = __uint_as_float((unsigned)hb << 16);
                yhi[c][j] = (short)hb;
                ylo[c][j] = (short)bf16_rne(vv[j] - hf);
            }
        }
    }

    float ps[4] = {}, pd[4] = {};
    const size_t brow0 = (size_t)l * K + q * 8;
#pragma unroll
    for (int nt = 0; nt < 16; nt += 2) {
        // X = Btp fragments ("A" operand) for tiles nt and nt+1
        const unsigned short* bh0 = Bhi + (size_t)(nt * 16) * K + brow0;
        const unsigned short* bl0 = Blo + (size_t)(nt * 16) * K + brow0;
        const unsigned short* bh1 = bh0 + (size_t)16 * K;
        const unsigned short* bl1 = bl0 + (size_t)16 * K;
        bf16x8 xh0[NC], xl0[NC], xh1[NC], xl1[NC];
#pragma unroll
        for (int c = 0; c < NC; ++c) {
            xh0[c] = *(const bf16x8*)(bh0 + c * 32);
            xl0[c] = *(const bf16x8*)(bl0 + c * 32);
            xh1[c] = *(const bf16x8*)(bh1 + c * 32);
            xl1[c] = *(const bf16x8*)(bl1 + c * 32);
        }
        f32x4 acc0 = {0.f, 0.f, 0.f, 0.f}, acc1 = {0.f, 0.f, 0.f, 0.f};
#pragma unroll
        for (int c = 0; c < NC; ++c) {
            acc0 = __builtin_amdgcn_mfma_f32_16x16x32_bf16(xh0[c], yhi[c], acc0, 0, 0, 0);
            acc1 = __builtin_amdgcn_mfma_f32_16x16x32_bf16(xh1[c], yhi[c], acc1, 0, 0, 0);
            acc0 = __builtin_amdgcn_mfma_f32_16x16x32_bf16(xl0[c], yhi[c], acc0, 0, 0, 0);
            acc1 = __builtin_amdgcn_mfma_f32_16x16x32_bf16(xl1[c], yhi[c], acc1, 0, 0, 0);
            acc0 = __builtin_amdgcn_mfma_f32_16x16x32_bf16(xh0[c], ylo[c], acc0, 0, 0, 0);
            acc1 = __builtin_amdgcn_mfma_f32_16x16x32_bf16(xh1[c], ylo[c], acc1, 0, 0, 0);
        }
        // packed h16 store + per-head alpha accumulation (j = ntile*16+q*4+r,
        // head = j&3 = r)
#pragma unroll
        for (int t = 0; t < 2; ++t) {
            f32x4 acc = t ? acc1 : acc0;
            int n0 = (nt + t) * 16 + q * 4;
            float4 av = *(const float4*)(aperm + n0);
            float4 dv = *(const float4*)(adperm + n0);
            ps[0] += acc[0] * av.x; pd[0] += acc[0] * dv.x;
            ps[1] += acc[1] * av.y; pd[1] += acc[1] * dv.y;
            ps[2] += acc[2] * av.z; pd[2] += acc[2] * dv.z;
            ps[3] += acc[3] * av.w; pd[3] += acc[3] * dv.w;
            __half2 p0 = __floats2half2_rn(acc[0], acc[1]);
            __half2 p1 = __floats2half2_rn(acc[2], acc[3]);
            uint2 pk = make_uint2(*(unsigned*)&p0, *(unsigned*)&p1);
            *(uint2*)(C16 + (size_t)(m0 + l) * 256 + n0) = pk;
        }
    }
    // reduce across q (lanes l, l+16, l+32, l+48 share node m0+l)
#pragma unroll
    for (int r = 0; r < 4; ++r) {
        ps[r] += __shfl_xor(ps[r], 16);
        ps[r] += __shfl_xor(ps[r], 32);
        pd[r] += __shfl_xor(pd[r], 16);
        pd[r] += __shfl_xor(pd[r], 32);
    }
    if (lane < 16) {
        *(float4*)(os + (size_t)(m0 + l) * 4) = make_float4(ps[0], ps[1], ps[2], ps[3]);
        *(float4*)(od + (size_t)(m0 + l) * 4) = make_float4(pd[0], pd[1], pd[2], pd[3]);
    }
}

__device__ __forceinline__ float lrelu_exp(float x) {
    x = x > 0.f ? x : 0.2f * x;
    return __expf(x);
}

// Wave per dst node; lane=dim; ONE 8B gather/edge; fdot2 inner op; 4-deep
// pipeline; LDS-staged (s, fp16-alpha). At fill-path roofline (~57us floor).
__global__ __launch_bounds__(256) void k_aggr(const int* __restrict__ rowptr,
                                              const int* __restrict__ csr_src,
                                              const float* __restrict__ as_,
                                              const float* __restrict__ ad_,
                                              const __half* __restrict__ h16,
                                              const float* __restrict__ bias,
                                              float* __restrict__ out) {
    __shared__ uint2 als16[4][64];
    __shared__ int sss[4][64];
    int w = threadIdx.x >> 6;
    int lane = threadIdx.x & 63;
    int d = blockIdx.x * 4 + w;
    if (d >= NN) return;
    int beg = rowptr[d], end = rowptr[d + 1];
    float4 adv = *(const float4*)(ad_ + d * 4);

    int s0 = 0;
    float4 u0 = make_float4(0.f, 0.f, 0.f, 0.f);
    float4 den = make_float4(0.f, 0.f, 0.f, 0.f);
    int i0 = beg + lane;
    if (i0 < end) {
        s0 = csr_src[i0];
        float4 sv = *(const float4*)(as_ + s0 * 4);
        u0.x = lrelu_exp(sv.x + adv.x);
        u0.y = lrelu_exp(sv.y + adv.y);
        u0.z = lrelu_exp(sv.z + adv.z);
        u0.w = lrelu_exp(sv.w + adv.w);
        den = u0;
    }
    for (int i = i0 + 64; i < end; i += 64) {
        int s = csr_src[i];
        float4 sv = *(const float4*)(as_ + s * 4);
        den.x += lrelu_exp(sv.x + adv.x);
        den.y += lrelu_exp(sv.y + adv.y);
        den.z += lrelu_exp(sv.z + adv.z);
        den.w += lrelu_exp(sv.w + adv.w);
    }
#pragma unroll
    for (int off = 32; off > 0; off >>= 1) {
        den.x += __shfl_xor(den.x, off);
        den.y += __shfl_xor(den.y, off);
        den.z += __shfl_xor(den.z, off);
        den.w += __shfl_xor(den.w, off);
    }
    float4 dinv = make_float4(0.25f / den.x, 0.25f / den.y,
                              0.25f / den.z, 0.25f / den.w);
    {
        __half2 q0 = __floats2half2_rn(u0.x * dinv.x, u0.y * dinv.y);
        __half2 q1 = __floats2half2_rn(u0.z * dinv.z, u0.w * dinv.w);
        als16[w][lane] = make_uint2(*(unsigned*)&q0, *(unsigned*)&q1);
        sss[w][lane] = s0;
    }

    int cnt = end - beg;
    if (cnt > 64) cnt = 64;
    int cnt4 = (cnt + 3) & ~3;
    float acc = 0.f;
    int4 sq = *(const int4*)&sss[w][0];
    uint2 r0 = *(const uint2*)(h16 + (size_t)sq.x * 256 + lane * 4);
    uint2 r1 = *(const uint2*)(h16 + (size_t)sq.y * 256 + lane * 4);
    uint2 r2 = *(const uint2*)(h16 + (size_t)sq.z * 256 + lane * 4);
    uint2 r3 = *(const uint2*)(h16 + (size_t)sq.w * 256 + lane * 4);
    for (int j = 0; j < cnt4; j += 4) {
        int jn = (j + 4) & 63;
        int4 sn = *(const int4*)&sss[w][jn];
        uint2 n0 = *(const uint2*)(h16 + (size_t)sn.x * 256 + lane * 4);
        uint2 n1 = *(const uint2*)(h16 + (size_t)sn.y * 256 + lane * 4);
        uint2 n2 = *(const uint2*)(h16 + (size_t)sn.z * 256 + lane * 4);
        uint2 n3 = *(const uint2*)(h16 + (size_t)sn.w * 256 + lane * 4);
        uint4 A01 = *(const uint4*)&als16[w][j];
        uint4 A23 = *(const uint4*)&als16[w][j + 2];
        acc = __builtin_amdgcn_fdot2(as_h2(r0.x), as_h2(A01.x), acc, false);
        acc = __builtin_amdgcn_fdot2(as_h2(r0.y), as_h2(A01.y), acc, false);
        acc = __builtin_amdgcn_fdot2(as_h2(r1.x), as_h2(A01.z), acc, false);
        acc = __builtin_amdgcn_fdot2(as_h2(r1.y), as_h2(A01.w), acc, false);
        acc = __builtin_amdgcn_fdot2(as_h2(r2.x), as_h2(A23.x), acc, false);
        acc = __builtin_amdgcn_fdot2(as_h2(r2.y), as_h2(A23.y), acc, false);
        acc = __builtin_amdgcn_fdot2(as_h2(r3.x), as_h2(A23.z), acc, false);
        acc = __builtin_amdgcn_fdot2(as_h2(r3.y), as_h2(A23.w), acc, false);
        r0 = n0; r1 = n1; r2 = n2; r3 = n3;
    }
    for (int chunk = beg + 64; chunk < end; chunk += 64) {
        int i = chunk + lane;
        int s = 0;
        float4 al = make_float4(0.f, 0.f, 0.f, 0.f);
        if (i < end) {
            s = csr_src[i];
            float4 sv = *(const float4*)(as_ + s * 4);
            al.x = lrelu_exp(sv.x + adv.x) * dinv.x;
            al.y = lrelu_exp(sv.y + adv.y) * dinv.y;
            al.z = lrelu_exp(sv.z + adv.z) * dinv.z;
            al.w = lrelu_exp(sv.w + adv.w) * dinv.w;
        }
        int cc = end - chunk;
        if (cc > 64) cc = 64;
        for (int j = 0; j < cc; ++j) {
            int sj = __shfl(s, j);
            float a0 = __shfl(al.x, j), a1 = __shfl(al.y, j);
            float a2 = __shfl(al.z, j), a3 = __shfl(al.w, j);
            uint2 raw = *(const uint2*)(h16 + (size_t)sj * 256 + lane * 4);
            float2 fa = __half22float2(*(const __half2*)&raw.x);
            float2 fb = __half22float2(*(const __half2*)&raw.y);
            acc += a0 * fa.x + a1 * fa.y + a2 * fb.x + a3 * fb.y;
        }
    }
    float v = acc + bias[lane];
    out[d * 64 + lane] = v > 0.f ? v : 0.f;
}

// batch is SORTED: binary-search per graph; 4 waves split the node loop.
__global__ __launch_bounds__(256) void k_pool_fc(const float* __restrict__ x3,
                                                 const int* __restrict__ batch,
                                                 const int* __restrict__ ei,
                                                 const float* __restrict__ fcW,
                                                 const float* __restrict__ fcb,
                                                 float* __restrict__ out) {
    __shared__ int sflag;
    int tid = threadIdx.x, lane = tid & 63, w = tid >> 6;
    int st = detect_stride(ei, tid, &sflag);
    int g = blockIdx.x;
    int lo = 0, hi = NN;
    while (lo < hi) { int mid = (lo + hi) >> 1; if (batch[(size_t)st * mid] < g) lo = mid + 1; else hi = mid; }
    int start = lo;
    hi = NN;
    while (lo < hi) { int mid = (lo + hi) >> 1; if (batch[(size_t)st * mid] < g + 1) lo = mid + 1; else hi = mid; }
    int end = lo;
    float sum = 0.f;
    for (int n = start + w; n < end; n += 4) sum += x3[n * 64 + lane];
    __shared__ float ls[4][64];
    ls[w][lane] = sum;
    __syncthreads();
    if (w == 0) {
        float c = (float)(end - start);
        if (c < 1.f) c = 1.f;
        float p = (ls[0][lane] + ls[1][lane] + ls[2][lane] + ls[3][lane]) / c;
#pragma unroll
        for (int o = 0; o < 16; ++o) {
            float v = p * fcW[lane * 16 + o];
#pragma unroll
            for (int off = 32; off > 0; off >>= 1) v += __shfl_down(v, off);
            if (lane == 0) out[g * 16 + o] = v + fcb[o];
        }
    }
}

extern "C" void kernel_launch(void* const* d_in, const int* in_sizes, int n_in,
                              void* d_out, int out_size, void* d_ws, size_t ws_size,
                              hipStream_t stream) {
    const float* x   = (const float*)d_in[0];
    const int*   ei  = (const int*)d_in[1];
    const int*   bat = (const int*)d_in[2];
    const float* W1  = (const float*)d_in[3];
    const float* a1s = (const float*)d_in[4];
    const float* a1d = (const float*)d_in[5];
    const float* b1  = (const float*)d_in[6];
    const float* W2  = (const float*)d_in[7];
    const float* a2s = (const float*)d_in[8];
    const float* a2d = (const float*)d_in[9];
    const float* b2  = (const float*)d_in[10];
    const float* fcW = (const float*)d_in[11];
    const float* fcb = (const float*)d_in[12];
    float* out = (float*)d_out;

    float* ws = (float*)d_ws;
    __half* h16  = (__half*)(ws + 256);           // [N,256] fp16 [n][dim][head]
    float* as_   = (float*)(h16 + (size_t)NN * 256);  // [N,4]
    float* ad_   = as_ + NN * 4;                  // [N,4]
    float* xacc  = ad_ + NN * 4;                  // [N,64]
    int* src32   = (int*)(xacc + (size_t)NN * 64);// [E]
    int* dst32   = src32 + ETOT;                  // [E]
    int* deg     = dst32 + ETOT;                  // [N]
    int* rowptr  = deg + NN;                      // [N+1]
    int* cursor  = rowptr + NN + 1;               // [N]
    int* csr_src = cursor + NN;                   // [E]
    int* bsum    = csr_src + ETOT;                // [NBLK]
    char* p = (char*)(bsum + NBLK);
    p = (char*)(((size_t)p + 255) & ~(size_t)255);
    unsigned short* bt1h = (unsigned short*)p; p += 256 * 128 * 2;
    unsigned short* bt1l = (unsigned short*)p; p += 256 * 128 * 2;
    unsigned short* bt2h = (unsigned short*)p; p += 256 * 64 * 2;
    unsigned short* bt2l = (unsigned short*)p; p += 256 * 64 * 2;
    float* ap1  = (float*)p; p += 256 * 4;
    float* adp1 = (float*)p; p += 256 * 4;
    float* ap2  = (float*)p; p += 256 * 4;
    float* adp2 = (float*)p; p += 256 * 4;

    const int wb = (NN * 64 + 255) / 256;  // 12500 wave-per-node blocks

    // ---- one-time per call: indices + dst-CSR + weight planes ----
    hipMemsetAsync(deg, 0, NN * sizeof(int), stream);
    k_prep<<<EB + 192, 256, 0, stream>>>(ei, src32, dst32, deg,
                                         W1, a1s, a1d, W2, a2s, a2d,
                                         bt1h, bt1l, bt2h, bt2l,
                                         ap1, adp1, ap2, adp2);
    k_blocksum<<<NBLK, 256, 0, stream>>>(deg, bsum);
    k_scan_final<<<NBLK, 256, 0, stream>>>(deg, bsum, rowptr, cursor);
    k_scatter<<<EB, 256, 0, stream>>>(src32, dst32, cursor, csr_src);

    const int gg = NN / 16;  // 3125 single-wave blocks, 16 nodes each (exact)
    // ---- layer 1 ----
    k_gemm_mfma<128><<<gg, 64, 0, stream>>>(x, bt1h, bt1l, ap1, adp1, h16, as_, ad_);
    k_aggr<<<wb, 256, 0, stream>>>(rowptr, csr_src, as_, ad_, h16, b1, xacc);
    // ---- layer 2 ----
    k_gemm_mfma<64><<<gg, 64, 0, stream>>>(xacc, bt2h, bt2l, ap2, adp2, h16, as_, ad_);
    k_aggr<<<wb, 256, 0, stream>>>(rowptr, csr_src, as_, ad_, h16, b2, xacc);
    // ---- pool + fc ----
    k_pool_fc<<<NG, 256, 0, stream>>>(xacc, bat, ei, fcW, fcb, out);
}

// Round 17
// 377.117 us; speedup vs baseline: 1.1136x; 1.1136x over previous
//
#include <hip/hip_runtime.h>
#include <hip/hip_bf16.h>
#include <hip/hip_fp16.h>

#define NN 50000
#define EE 800000
#define ETOT 850000
#define NG 500
#define NBLK ((NN + 255) / 256)  // 196
#define EB ((ETOT + 255) / 256)  // 3321

typedef __attribute__((ext_vector_type(8))) short bf16x8;
typedef __attribute__((ext_vector_type(4))) float f32x4;
typedef _Float16 h2f __attribute__((ext_vector_type(2)));

__device__ __forceinline__ h2f as_h2(unsigned u) {
    union { unsigned u; h2f h; } x;
    x.u = u;
    return x.h;
}

__device__ __forceinline__ unsigned short bf16_rne(float v) {
    unsigned u = __float_as_uint(v);
    unsigned r = u + 0x7FFFu + ((u >> 16) & 1u);
    return (unsigned short)(r >> 16);
}

// Per-block int64/int32 detect: node ids < 50000 => int64 has all-odd-words 0.
__device__ __forceinline__ int detect_stride(const int* __restrict__ ei,
                                             int tid, int* sflag) {
    if (tid < 64) {
        unsigned long long b = __ballot(ei[2 * tid + 1] != 0);
        if (tid == 0) *sflag = b ? 1 : 2;
    }
    __syncthreads();
    return *sflag;
}

// W [K][256] fp32 -> transposed, column-permuted bf16 hi/lo planes [256][K];
// permuted col j = dim*4+head. Also permuted a_src/a_dst.
__device__ __forceinline__ void prepw_one(const float* __restrict__ W,
                                          const float* __restrict__ asrc,
                                          const float* __restrict__ adst,
                                          unsigned short* __restrict__ bhi,
                                          unsigned short* __restrict__ blo,
                                          float* __restrict__ ap,
                                          float* __restrict__ adp,
                                          int K, int t) {
    int j = t / K, k = t - j * K;
    int d = j >> 2, h = j & 3;
    float v = W[k * 256 + h * 64 + d];
    unsigned short hb = bf16_rne(v);
    float hf = __uint_as_float((unsigned)hb << 16);
    bhi[t] = hb;
    blo[t] = bf16_rne(v - hf);
    if (k == 0) { ap[j] = asrc[h * 64 + d]; adp[j] = adst[h * 64 + d]; }
}

// Edge prep (int32 src/dst + self-loops + degree histogram) fused with
// both layers' weight prep in the tail blocks.
__global__ __launch_bounds__(256) void k_prep(
        const int* __restrict__ ei, int* __restrict__ src32,
        int* __restrict__ dst32, int* __restrict__ deg,
        const float* __restrict__ W1, const float* __restrict__ a1s,
        const float* __restrict__ a1d, const float* __restrict__ W2,
        const float* __restrict__ a2s, const float* __restrict__ a2d,
        unsigned short* __restrict__ b1h, unsigned short* __restrict__ b1l,
        unsigned short* __restrict__ b2h, unsigned short* __restrict__ b2l,
        float* __restrict__ ap1, float* __restrict__ adp1,
        float* __restrict__ ap2, float* __restrict__ adp2) {
    int blk = blockIdx.x;
    if (blk >= EB) {  // weight-prep tail
        int g = blk - EB;
        if (g < 128)
            prepw_one(W1, a1s, a1d, b1h, b1l, ap1, adp1, 128, g * 256 + threadIdx.x);
        else
            prepw_one(W2, a2s, a2d, b2h, b2l, ap2, adp2, 64, (g - 128) * 256 + threadIdx.x);
        return;
    }
    __shared__ int sflag;
    int tid = threadIdx.x;
    int st = detect_stride(ei, tid, &sflag);
    int e = blk * 256 + tid;
    if (e >= ETOT) return;
    int s, d;
    if (e < EE) {
        s = ei[(size_t)st * e];
        d = ei[(size_t)st * (EE + e)];
    } else {
        s = d = e - EE;  // self-loop
    }
    src32[e] = s;
    dst32[e] = d;
    atomicAdd(&deg[d], 1);
}

__global__ __launch_bounds__(256) void k_blocksum(const int* __restrict__ deg,
                                                  int* __restrict__ bsum) {
    __shared__ int l[256];
    int gid = blockIdx.x * 256 + threadIdx.x;
    int tid = threadIdx.x;
    l[tid] = (gid < NN) ? deg[gid] : 0;
    __syncthreads();
    for (int o = 128; o > 0; o >>= 1) {
        if (tid < o) l[tid] += l[tid + o];
        __syncthreads();
    }
    if (tid == 0) bsum[blockIdx.x] = l[0];
}

// Each block re-scans bsum[196] locally, then scans its 256-chunk of deg.
__global__ __launch_bounds__(256) void k_scan_final(const int* __restrict__ deg,
                                                    const int* __restrict__ bsum,
                                                    int* __restrict__ rowptr,
                                                    int* __restrict__ cursor) {
    __shared__ int lb[256];
    __shared__ int l[256];
    int tid = threadIdx.x;
    int vb = (tid < NBLK) ? bsum[tid] : 0;
    lb[tid] = vb;
    __syncthreads();
    for (int d = 1; d < 256; d <<= 1) {
        int t = (tid >= d) ? lb[tid - d] : 0;
        __syncthreads();
        lb[tid] += t;
        __syncthreads();
    }
    int boffb = lb[blockIdx.x] - bsum[blockIdx.x];
    int gid = blockIdx.x * 256 + tid;
    int v = (gid < NN) ? deg[gid] : 0;
    l[tid] = v;
    __syncthreads();
    for (int d = 1; d < 256; d <<= 1) {
        int t = (tid >= d) ? l[tid - d] : 0;
        __syncthreads();
        l[tid] += t;
        __syncthreads();
    }
    int ex = l[tid] - v + boffb;
    if (gid < NN) { rowptr[gid] = ex; cursor[gid] = ex; }
    if (gid == 0) rowptr[NN] = ETOT;
}

__global__ __launch_bounds__(256) void k_scatter(const int* __restrict__ src32,
                                                 const int* __restrict__ dst32,
                                                 int* __restrict__ cursor,
                                                 int* __restrict__ csr_src) {
    int e = blockIdx.x * 256 + threadIdx.x;
    if (e >= ETOT) return;
    int pos = atomicAdd(&cursor[dst32[e]], 1);
    csr_src[pos] = src32[e];
}

// C[M,256] = A[M,K] @ B[K,256] via MFMA 16x16x32 bf16-split (fp32-grade).
// Wave = 32 rows x 16 n-tiles: measured-best config (r12). n-split (r14),
// B-prefetch (r15), and C^T (r16) all regressed -- this shape maximizes
// per-wave B reuse at the occupancy this tiny GEMM can sustain.
template <int K>
__global__ __launch_bounds__(64) void k_gemm_mfma(
        const float* __restrict__ A,
        const unsigned short* __restrict__ Bhi,
        const unsigned short* __restrict__ Blo,
        const float* __restrict__ aperm,
        const float* __restrict__ adperm,
        __half* __restrict__ C16,
        float* __restrict__ os,
        float* __restrict__ od, int M) {
    const int NC = K / 32;
    int lane = threadIdx.x;
    int l = lane & 15, q = lane >> 4;
    int m0 = blockIdx.x * 32;

    bf16x8 ahi[2][NC], alo[2][NC];
#pragma unroll
    for (int t = 0; t < 2; ++t) {
        int row = m0 + t * 16 + l;
        if (row >= M) row = M - 1;  // clamp loads; stores guarded below
        const float* arow = A + (size_t)row * K + q * 8;
#pragma unroll
        for (int c = 0; c < NC; ++c) {
            float4 v0 = *(const float4*)(arow + c * 32);
            float4 v1 = *(const float4*)(arow + c * 32 + 4);
            float vv[8] = {v0.x, v0.y, v0.z, v0.w, v1.x, v1.y, v1.z, v1.w};
#pragma unroll
            for (int j = 0; j < 8; ++j) {
                unsigned short hb = bf16_rne(vv[j]);
                float hf = __uint_as_float((unsigned)hb << 16);
                ahi[t][c][j] = (short)hb;
                alo[t][c][j] = (short)bf16_rne(vv[j] - hf);
            }
        }
    }

    float ps[2][4] = {}, pd[2][4] = {};
    const size_t brow = (size_t)l * K + q * 8;
#pragma unroll 2
    for (int n = 0; n < 16; ++n) {
        const unsigned short* bh = Bhi + (size_t)(n * 16) * K + brow;
        const unsigned short* bl = Blo + (size_t)(n * 16) * K + brow;
        bf16x8 bhf[NC], blf[NC];
#pragma unroll
        for (int c = 0; c < NC; ++c) {
            bhf[c] = *(const bf16x8*)(bh + c * 32);
            blf[c] = *(const bf16x8*)(bl + c * 32);
        }
        f32x4 acc0 = {0.f, 0.f, 0.f, 0.f}, acc1 = {0.f, 0.f, 0.f, 0.f};
#pragma unroll
        for (int c = 0; c < NC; ++c) {
            acc0 = __builtin_amdgcn_mfma_f32_16x16x32_bf16(ahi[0][c], bhf[c], acc0, 0, 0, 0);
            acc1 = __builtin_amdgcn_mfma_f32_16x16x32_bf16(ahi[1][c], bhf[c], acc1, 0, 0, 0);
            acc0 = __builtin_amdgcn_mfma_f32_16x16x32_bf16(ahi[0][c], blf[c], acc0, 0, 0, 0);
            acc1 = __builtin_amdgcn_mfma_f32_16x16x32_bf16(ahi[1][c], blf[c], acc1, 0, 0, 0);
            acc0 = __builtin_amdgcn_mfma_f32_16x16x32_bf16(alo[0][c], bhf[c], acc0, 0, 0, 0);
            acc1 = __builtin_amdgcn_mfma_f32_16x16x32_bf16(alo[1][c], bhf[c], acc1, 0, 0, 0);
        }
        float av = aperm[n * 16 + l], dv = adperm[n * 16 + l];
#pragma unroll
        for (int r = 0; r < 4; ++r) {
            ps[0][r] += acc0[r] * av; pd[0][r] += acc0[r] * dv;
            ps[1][r] += acc1[r] * av; pd[1][r] += acc1[r] * dv;
            int gm0 = m0 + q * 4 + r;
            if (gm0 < M) C16[(size_t)gm0 * 256 + n * 16 + l] = __float2half(acc0[r]);
            int gm1 = m0 + 16 + q * 4 + r;
            if (gm1 < M) C16[(size_t)gm1 * 256 + n * 16 + l] = __float2half(acc1[r]);
        }
    }
#pragma unroll
    for (int t = 0; t < 2; ++t)
#pragma unroll
        for (int r = 0; r < 4; ++r) {
            ps[t][r] += __shfl_xor(ps[t][r], 4);
            ps[t][r] += __shfl_xor(ps[t][r], 8);
            pd[t][r] += __shfl_xor(pd[t][r], 4);
            pd[t][r] += __shfl_xor(pd[t][r], 8);
        }
    if (l < 4) {
#pragma unroll
        for (int t = 0; t < 2; ++t)
#pragma unroll
            for (int r = 0; r < 4; ++r) {
                int gm = m0 + t * 16 + q * 4 + r;
                if (gm < M) {
                    os[(size_t)gm * 4 + l] = ps[t][r];
                    od[(size_t)gm * 4 + l] = pd[t][r];
                }
            }
    }
}

__device__ __forceinline__ float lrelu_exp(float x) {
    x = x > 0.f ? x : 0.2f * x;
    return __expf(x);
}

// Wave per dst node; lane=dim; ONE 8B gather/edge; fdot2 inner op; 4-deep
// pipeline; LDS-staged (s, fp16-alpha). At random-gather fill-path roofline:
// FETCH pinned at 206 MB / ~3.55 TB/s across 5 issue-side variants.
__global__ __launch_bounds__(256) void k_aggr(const int* __restrict__ rowptr,
                                              const int* __restrict__ csr_src,
                                              const float* __restrict__ as_,
                                              const float* __restrict__ ad_,
                                              const __half* __restrict__ h16,
                                              const float* __restrict__ bias,
                                              float* __restrict__ out) {
    __shared__ uint2 als16[4][64];
    __shared__ int sss[4][64];
    int w = threadIdx.x >> 6;
    int lane = threadIdx.x & 63;
    int d = blockIdx.x * 4 + w;
    if (d >= NN) return;
    int beg = rowptr[d], end = rowptr[d + 1];
    float4 adv = *(const float4*)(ad_ + d * 4);

    int s0 = 0;
    float4 u0 = make_float4(0.f, 0.f, 0.f, 0.f);
    float4 den = make_float4(0.f, 0.f, 0.f, 0.f);
    int i0 = beg + lane;
    if (i0 < end) {
        s0 = csr_src[i0];
        float4 sv = *(const float4*)(as_ + s0 * 4);
        u0.x = lrelu_exp(sv.x + adv.x);
        u0.y = lrelu_exp(sv.y + adv.y);
        u0.z = lrelu_exp(sv.z + adv.z);
        u0.w = lrelu_exp(sv.w + adv.w);
        den = u0;
    }
    for (int i = i0 + 64; i < end; i += 64) {
        int s = csr_src[i];
        float4 sv = *(const float4*)(as_ + s * 4);
        den.x += lrelu_exp(sv.x + adv.x);
        den.y += lrelu_exp(sv.y + adv.y);
        den.z += lrelu_exp(sv.z + adv.z);
        den.w += lrelu_exp(sv.w + adv.w);
    }
#pragma unroll
    for (int off = 32; off > 0; off >>= 1) {
        den.x += __shfl_xor(den.x, off);
        den.y += __shfl_xor(den.y, off);
        den.z += __shfl_xor(den.z, off);
        den.w += __shfl_xor(den.w, off);
    }
    float4 dinv = make_float4(0.25f / den.x, 0.25f / den.y,
                              0.25f / den.z, 0.25f / den.w);
    {
        __half2 q0 = __floats2half2_rn(u0.x * dinv.x, u0.y * dinv.y);
        __half2 q1 = __floats2half2_rn(u0.z * dinv.z, u0.w * dinv.w);
        als16[w][lane] = make_uint2(*(unsigned*)&q0, *(unsigned*)&q1);
        sss[w][lane] = s0;
    }

    int cnt = end - beg;
    if (cnt > 64) cnt = 64;
    int cnt4 = (cnt + 3) & ~3;
    float acc = 0.f;
    int4 sq = *(const int4*)&sss[w][0];
    uint2 r0 = *(const uint2*)(h16 + (size_t)sq.x * 256 + lane * 4);
    uint2 r1 = *(const uint2*)(h16 + (size_t)sq.y * 256 + lane * 4);
    uint2 r2 = *(const uint2*)(h16 + (size_t)sq.z * 256 + lane * 4);
    uint2 r3 = *(const uint2*)(h16 + (size_t)sq.w * 256 + lane * 4);
    for (int j = 0; j < cnt4; j += 4) {
        int jn = (j + 4) & 63;
        int4 sn = *(const int4*)&sss[w][jn];
        uint2 n0 = *(const uint2*)(h16 + (size_t)sn.x * 256 + lane * 4);
        uint2 n1 = *(const uint2*)(h16 + (size_t)sn.y * 256 + lane * 4);
        uint2 n2 = *(const uint2*)(h16 + (size_t)sn.z * 256 + lane * 4);
        uint2 n3 = *(const uint2*)(h16 + (size_t)sn.w * 256 + lane * 4);
        uint4 A01 = *(const uint4*)&als16[w][j];
        uint4 A23 = *(const uint4*)&als16[w][j + 2];
        acc = __builtin_amdgcn_fdot2(as_h2(r0.x), as_h2(A01.x), acc, false);
        acc = __builtin_amdgcn_fdot2(as_h2(r0.y), as_h2(A01.y), acc, false);
        acc = __builtin_amdgcn_fdot2(as_h2(r1.x), as_h2(A01.z), acc, false);
        acc = __builtin_amdgcn_fdot2(as_h2(r1.y), as_h2(A01.w), acc, false);
        acc = __builtin_amdgcn_fdot2(as_h2(r2.x), as_h2(A23.x), acc, false);
        acc = __builtin_amdgcn_fdot2(as_h2(r2.y), as_h2(A23.y), acc, false);
        acc = __builtin_amdgcn_fdot2(as_h2(r3.x), as_h2(A23.z), acc, false);
        acc = __builtin_amdgcn_fdot2(as_h2(r3.y), as_h2(A23.w), acc, false);
        r0 = n0; r1 = n1; r2 = n2; r3 = n3;
    }
    for (int chunk = beg + 64; chunk < end; chunk += 64) {
        int i = chunk + lane;
        int s = 0;
        float4 al = make_float4(0.f, 0.f, 0.f, 0.f);
        if (i < end) {
            s = csr_src[i];
            float4 sv = *(const float4*)(as_ + s * 4);
            al.x = lrelu_exp(sv.x + adv.x) * dinv.x;
            al.y = lrelu_exp(sv.y + adv.y) * dinv.y;
            al.z = lrelu_exp(sv.z + adv.z) * dinv.z;
            al.w = lrelu_exp(sv.w + adv.w) * dinv.w;
        }
        int cc = end - chunk;
        if (cc > 64) cc = 64;
        for (int j = 0; j < cc; ++j) {
            int sj = __shfl(s, j);
            float a0 = __shfl(al.x, j), a1 = __shfl(al.y, j);
            float a2 = __shfl(al.z, j), a3 = __shfl(al.w, j);
            uint2 raw = *(const uint2*)(h16 + (size_t)sj * 256 + lane * 4);
            float2 fa = __half22float2(*(const __half2*)&raw.x);
            float2 fb = __half22float2(*(const __half2*)&raw.y);
            acc += a0 * fa.x + a1 * fa.y + a2 * fb.x + a3 * fb.y;
        }
    }
    float v = acc + bias[lane];
    out[d * 64 + lane] = v > 0.f ? v : 0.f;
}

// batch is SORTED: binary-search per graph; 4 waves split the node loop.
__global__ __launch_bounds__(256) void k_pool_fc(const float* __restrict__ x3,
                                                 const int* __restrict__ batch,
                                                 const int* __restrict__ ei,
                                                 const float* __restrict__ fcW,
                                                 const float* __restrict__ fcb,
                                                 float* __restrict__ out) {
    __shared__ int sflag;
    int tid = threadIdx.x, lane = tid & 63, w = tid >> 6;
    int st = detect_stride(ei, tid, &sflag);
    int g = blockIdx.x;
    int lo = 0, hi = NN;
    while (lo < hi) { int mid = (lo + hi) >> 1; if (batch[(size_t)st * mid] < g) lo = mid + 1; else hi = mid; }
    int start = lo;
    hi = NN;
    while (lo < hi) { int mid = (lo + hi) >> 1; if (batch[(size_t)st * mid] < g + 1) lo = mid + 1; else hi = mid; }
    int end = lo;
    float sum = 0.f;
    for (int n = start + w; n < end; n += 4) sum += x3[n * 64 + lane];
    __shared__ float ls[4][64];
    ls[w][lane] = sum;
    __syncthreads();
    if (w == 0) {
        float c = (float)(end - start);
        if (c < 1.f) c = 1.f;
        float p = (ls[0][lane] + ls[1][lane] + ls[2][lane] + ls[3][lane]) / c;
#pragma unroll
        for (int o = 0; o < 16; ++o) {
            float v = p * fcW[lane * 16 + o];
#pragma unroll
            for (int off = 32; off > 0; off >>= 1) v += __shfl_down(v, off);
            if (lane == 0) out[g * 16 + o] = v + fcb[o];
        }
    }
}

extern "C" void kernel_launch(void* const* d_in, const int* in_sizes, int n_in,
                              void* d_out, int out_size, void* d_ws, size_t ws_size,
                              hipStream_t stream) {
    const float* x   = (const float*)d_in[0];
    const int*   ei  = (const int*)d_in[1];
    const int*   bat = (const int*)d_in[2];
    const float* W1  = (const float*)d_in[3];
    const float* a1s = (const float*)d_in[4];
    const float* a1d = (const float*)d_in[5];
    const float* b1  = (const float*)d_in[6];
    const float* W2  = (const float*)d_in[7];
    const float* a2s = (const float*)d_in[8];
    const float* a2d = (const float*)d_in[9];
    const float* b2  = (const float*)d_in[10];
    const float* fcW = (const float*)d_in[11];
    const float* fcb = (const float*)d_in[12];
    float* out = (float*)d_out;

    float* ws = (float*)d_ws;
    __half* h16  = (__half*)(ws + 256);           // [N,256] fp16 [n][dim][head]
    float* as_   = (float*)(h16 + (size_t)NN * 256);  // [N,4]
    float* ad_   = as_ + NN * 4;                  // [N,4]
    float* xacc  = ad_ + NN * 4;                  // [N,64]
    int* src32   = (int*)(xacc + (size_t)NN * 64);// [E]
    int* dst32   = src32 + ETOT;                  // [E]
    int* deg     = dst32 + ETOT;                  // [N]
    int* rowptr  = deg + NN;                      // [N+1]
    int* cursor  = rowptr + NN + 1;               // [N]
    int* csr_src = cursor + NN;                   // [E]
    int* bsum    = csr_src + ETOT;                // [NBLK]
    char* p = (char*)(bsum + NBLK);
    p = (char*)(((size_t)p + 255) & ~(size_t)255);
    unsigned short* bt1h = (unsigned short*)p; p += 256 * 128 * 2;
    unsigned short* bt1l = (unsigned short*)p; p += 256 * 128 * 2;
    unsigned short* bt2h = (unsigned short*)p; p += 256 * 64 * 2;
    unsigned short* bt2l = (unsigned short*)p; p += 256 * 64 * 2;
    float* ap1  = (float*)p; p += 256 * 4;
    float* adp1 = (float*)p; p += 256 * 4;
    float* ap2  = (float*)p; p += 256 * 4;
    float* adp2 = (float*)p; p += 256 * 4;

    const int wb = (NN * 64 + 255) / 256;  // 12500 wave-per-node blocks

    // ---- one-time per call: indices + dst-CSR + weight planes ----
    hipMemsetAsync(deg, 0, NN * sizeof(int), stream);
    k_prep<<<EB + 192, 256, 0, stream>>>(ei, src32, dst32, deg,
                                         W1, a1s, a1d, W2, a2s, a2d,
                                         bt1h, bt1l, bt2h, bt2l,
                                         ap1, adp1, ap2, adp2);
    k_blocksum<<<NBLK, 256, 0, stream>>>(deg, bsum);
    k_scan_final<<<NBLK, 256, 0, stream>>>(deg, bsum, rowptr, cursor);
    k_scatter<<<EB, 256, 0, stream>>>(src32, dst32, cursor, csr_src);

    const int gg = (NN + 31) / 32;  // 1563 single-wave blocks, 32 rows each
    // ---- layer 1 ----
    k_gemm_mfma<128><<<gg, 64, 0, stream>>>(x, bt1h, bt1l, ap1, adp1, h16, as_, ad_, NN);
    k_aggr<<<wb, 256, 0, stream>>>(rowptr, csr_src, as_, ad_, h16, b1, xacc);
    // ---- layer 2 ----
    k_gemm_mfma<64><<<gg, 64, 0, stream>>>(xacc, bt2h, bt2l, ap2, adp2, h16, as_, ad_, NN);
    k_aggr<<<wb, 256, 0, stream>>>(rowptr, csr_src, as_, ad_, h16, b2, xacc);
    // ---- pool + fc ----
    k_pool_fc<<<NG, 256, 0, stream>>>(xacc, bat, ei, fcW, fcb, out);
}